// Round 14
// baseline (295.326 us; speedup 1.0000x reference)
//
#include <hip/hip_runtime.h>

// ---------------------------------------------------------------------------
// Local windowed attention, B=8 N=8192 D=512, WS=128, lookback=1.
//   k_cvt : fp32 -> bf16 convert of x and weights (scratch in d_out).
//   k_qkv : merged Q/K/V projection GEMM (r6 form). Q,K row-major bf16;
//           V in Vt3[b][key/32][dv][key%32] bf16 with key-octet XOR swizzle
//           (octet_phys = octet ^ (dv&3)) so PV's LDS reads are ~2-way.
//   k_attn: swapped-operand flash attention: S^T = mfma(K,Q) puts P per-lane
//           (q = lane&15) -> softmax is in-register (no P LDS!), P repacked
//           to PV fragments via 64 shfl. LDS = 64KB (K dbuf / V dbuf union)
//           -> 2 blocks/CU. PV = mfma(Vt,P) computing O^T; dv in 2 halves.
// ---------------------------------------------------------------------------

typedef __bf16 bf16x8 __attribute__((ext_vector_type(8)));
typedef float f32x4 __attribute__((ext_vector_type(4)));
typedef unsigned short u16x8 __attribute__((ext_vector_type(8)));

#define BATCH 8
#define SEQ   8192
#define DIM   512
#define NWIN  64
#define TOKS  (BATCH * SEQ)          // 65536
#define WSELEM ((size_t)TOKS * DIM)  // 33554432 elements per Q/K/V buffer

__device__ __forceinline__ unsigned short f2b(float f) {
    union { float f; unsigned int u; } c; c.f = f;
    unsigned int u = c.u;
    return (unsigned short)((u + 0x7FFFu + ((u >> 16) & 1u)) >> 16);
}
__device__ __forceinline__ unsigned int pkb(float a, float b) {
    return (unsigned int)f2b(a) | ((unsigned int)f2b(b) << 16);
}

// XOR swizzle for [rows][64]-ushort LDS tiles (128B rows).
__device__ __forceinline__ int swz64(int row, int col) {
    return (row * 64 + col) ^ ((row & 7) << 3);
}

__device__ __forceinline__ void gload_lds16(const void* g, void* l) {
    __builtin_amdgcn_global_load_lds(
        (const __attribute__((address_space(1))) void*)g,
        (__attribute__((address_space(3))) void*)l, 16, 0, 0);
}

// ===========================================================================
// Kernel 0: fp32 -> bf16 bulk convert
// ===========================================================================
__global__ __launch_bounds__(256) void k_cvt(const float* __restrict__ s,
                                             unsigned short* __restrict__ d,
                                             int n8) {
    const int stride = gridDim.x * blockDim.x;
    for (int i = blockIdx.x * blockDim.x + threadIdx.x; i < n8; i += stride) {
        const float4 a = ((const float4*)s)[2 * i];
        const float4 b = ((const float4*)s)[2 * i + 1];
        u16x8 v;
        v[0] = f2b(a.x); v[1] = f2b(a.y); v[2] = f2b(a.z); v[3] = f2b(a.w);
        v[4] = f2b(b.x); v[5] = f2b(b.y); v[6] = f2b(b.z); v[7] = f2b(b.w);
        ((u16x8*)d)[i] = v;
    }
}

// ===========================================================================
// Kernel 1: merged QKV projection GEMM (r6). grid = 2048, block = 256.
// ===========================================================================
__global__ __launch_bounds__(256, 2) void k_qkv(
    const unsigned short* __restrict__ xb, const unsigned short* __restrict__ wb,
    const float* __restrict__ bq, const float* __restrict__ bk,
    const float* __restrict__ bv,
    unsigned short* __restrict__ qo, unsigned short* __restrict__ ko,
    unsigned short* __restrict__ vto)
{
    __shared__ __align__(16) unsigned short sm[32768]; // Xs|Wq|Wk|Wv; V-epi T[128][129] aliases
    unsigned short* Xs = sm;

    int bid = (int)blockIdx.x;
    bid = (bid & 7) * 256 + (bid >> 3);   // XCD-contiguous chunks
    const int mt = bid >> 2, nt = bid & 3;
    const int rbase = mt << 7;            // token row base
    const int cbase = nt << 7;            // output feature base

    const unsigned short* __restrict__ xsrc0 = xb + ((size_t)rbase << 9);
    const unsigned short* __restrict__ wsrc0 = wb + ((size_t)cbase << 9);

    const int tid  = threadIdx.x;
    const int lane = tid & 63;
    const int wid  = tid >> 6;
    const int wm = wid >> 1, wn = wid & 1;
    const int l15 = lane & 15, lg = lane >> 4;

    f32x4 acc[3][4][4];
#pragma unroll
    for (int s = 0; s < 3; ++s)
#pragma unroll
        for (int m = 0; m < 4; ++m)
#pragma unroll
            for (int n = 0; n < 4; ++n) acc[s][m][n] = (f32x4){0.f, 0.f, 0.f, 0.f};

    const int srow = tid >> 3;            // 0..31
    const int gs   = ((tid & 7) ^ (srow & 7)) << 3;  // src 16B slot (swizzled)
    const int ldso = tid << 3;

    for (int ks = 0; ks < 8; ++ks) {
        const int kc = ks << 6;
#pragma unroll
        for (int i = 0; i < 4; ++i) {
            const int row = (i << 5) + srow;
            gload_lds16(xsrc0 + ((size_t)row << 9) + kc + gs, Xs + (i << 11) + ldso);
        }
#pragma unroll
        for (int ws = 0; ws < 3; ++ws) {
#pragma unroll
            for (int i = 0; i < 4; ++i) {
                const int row = (i << 5) + srow;
                gload_lds16(wsrc0 + ((size_t)ws << 18) + ((size_t)row << 9) + kc + gs,
                            sm + 8192 + (ws << 13) + (i << 11) + ldso);
            }
        }
        __syncthreads();
#pragma unroll
        for (int kk = 0; kk < 64; kk += 32) {
            const int cu = kk + (lg << 3);
            bf16x8 af[4];
#pragma unroll
            for (int m = 0; m < 4; ++m)
                af[m] = *(const bf16x8*)&Xs[swz64((wm << 6) + (m << 4) + l15, cu)];
#pragma unroll
            for (int ws = 0; ws < 3; ++ws) {
                const unsigned short* Wsb = sm + 8192 + (ws << 13);
                bf16x8 bfr[4];
#pragma unroll
                for (int n = 0; n < 4; ++n)
                    bfr[n] = *(const bf16x8*)&Wsb[swz64((wn << 6) + (n << 4) + l15, cu)];
#pragma unroll
                for (int m = 0; m < 4; ++m)
#pragma unroll
                    for (int n = 0; n < 4; ++n)
                        acc[ws][m][n] = __builtin_amdgcn_mfma_f32_16x16x32_bf16(
                            af[m], bfr[n], acc[ws][m][n], 0, 0, 0);
            }
        }
        __syncthreads();
    }

    // ---- Q/K epilogues: row-major bf16 stores
#pragma unroll
    for (int ws = 0; ws < 2; ++ws) {
        unsigned short* __restrict__ out = ws ? ko : qo;
        const float* __restrict__ bias = ws ? bk : bq;
#pragma unroll
        for (int n = 0; n < 4; ++n) {
            const int col = cbase + (wn << 6) + (n << 4) + l15;
            const float bv_ = bias[col];
#pragma unroll
            for (int m = 0; m < 4; ++m)
#pragma unroll
                for (int j = 0; j < 4; ++j) {
                    const int row = rbase + (wm << 6) + (m << 4) + (lg << 2) + j;
                    out[(size_t)row * DIM + col] = f2b(acc[ws][m][n][j] + bv_);
                }
        }
    }
    // ---- V epilogue: transpose via LDS T[128][129], then wave-contiguous
    //      1KB stores to Vt3[b][key/32][dv][key%32], key-octet XOR'd by dv&3
#pragma unroll
    for (int n = 0; n < 4; ++n) {
        const int dv = (wn << 6) + (n << 4) + l15;
        const float bv_ = bv[cbase + dv];
#pragma unroll
        for (int m = 0; m < 4; ++m)
#pragma unroll
            for (int j = 0; j < 4; ++j) {
                const int tok = (wm << 6) + (m << 4) + (lg << 2) + j;
                sm[tok * 129 + dv] = f2b(acc[2][m][n][j] + bv_);
            }
    }
    __syncthreads();
    {
        const int batch = rbase >> 13;
        const int c5_0  = (rbase & 8191) >> 5;   // key-chunk base (mult of 4)
#pragma unroll
        for (int s = 0; s < 8; ++s) {
            const int c5sel = s & 3, dvh = s >> 2;
            const int dvl  = (dvh << 6) + (wid << 4) + (lane >> 2);  // 0..127
            const int keyo = (lane & 3) << 3;                        // 0,8,16,24
            const int tok0 = (c5sel << 5) + keyo;
            u16x8 v;
#pragma unroll
            for (int j = 0; j < 8; ++j) v[j] = sm[(tok0 + j) * 129 + dvl];
            *(u16x8*)&vto[((size_t)((batch * 256 + c5_0 + c5sel) * 512
                                    + cbase + dvl) << 5)
                          + (keyo ^ ((dvl & 3) << 3))] = v;
        }
    }
}

// ===========================================================================
// Kernel 2: swapped-operand windowed attention. grid = 512 x 512thr (8 waves).
// Wave w owns q-rows [w*16, w*16+16); within a lane, q = lane&15.
// LDS 64KB: phase A K dbuf 2x32KB; phase B V dbuf 2x16KB (aliases). 2 blk/CU.
// ===========================================================================
__global__ __launch_bounds__(512, 4) void k_attn(
    const unsigned short* __restrict__ q,
    const unsigned short* __restrict__ k,
    const unsigned short* __restrict__ vt3,
    float* __restrict__ out)
{
    __shared__ __align__(16) unsigned short Kb[32768];   // 64KB, reused for V

    int bid = (int)blockIdx.x;
    bid = (bid & 7) * 64 + (bid >> 3);    // XCD-chunked: one batch per XCD
    const int b = bid >> 6, w = bid & 63;
    const int tid  = threadIdx.x;
    const int lane = tid & 63, wid = tid >> 6;
    const int l15 = lane & 15, lg = lane >> 4;
    const int kstart = (w - 1) << 7;
    const size_t qrow0 = ((size_t)b << 13) + ((size_t)w << 7);
    const size_t kbase = (size_t)b << 13;

    const int srow = tid >> 3;            // 0..63
    const int s0   = tid & 7;

    // ---------------- phase A: S^T = K Q^T (per-wave 256k x 16q, inner 512) -
    f32x4 acc[16];
#pragma unroll
    for (int n = 0; n < 16; ++n) acc[n] = (f32x4){0.f, 0.f, 0.f, 0.f};

    auto stageK = [&](int buf, int ds) {
#pragma unroll
        for (int i = 0; i < 4; ++i) {
            const int r = (i << 6) + srow;
            int krow = kstart + r; krow = krow < 0 ? 0 : krow;  // masked anyway
            gload_lds16(k + (kbase + krow) * DIM + (ds << 6) + ((s0 ^ (r & 7)) << 3),
                        Kb + (buf << 14) + (i << 12) + (tid << 3));
        }
    };

    stageK(0, 0);
    stageK(1, 1);
    __syncthreads();
#pragma unroll
    for (int ds = 0; ds < 8; ++ds) {
        const unsigned short* Kc = Kb + ((ds & 1) << 14);
#pragma unroll
        for (int kk2 = 0; kk2 < 2; ++kk2) {
            const int cu = (kk2 << 5) + (lg << 3);
            const bf16x8 qf = *(const bf16x8*)
                &q[(qrow0 + (wid << 4) + l15) * DIM + (ds << 6) + cu];
#pragma unroll
            for (int n = 0; n < 16; ++n) {
                const bf16x8 kf = *(const bf16x8*)&Kc[swz64((n << 4) + l15, cu)];
                // SWAPPED: A=K, B=Q -> acc[n][j] = S[q=l15][key=16n+lg*4+j]
                acc[n] = __builtin_amdgcn_mfma_f32_16x16x32_bf16(kf, qf, acc[n], 0, 0, 0);
            }
        }
        __syncthreads();
        if (ds + 2 < 8) stageK(ds & 1, ds + 2);  // 1-deep pipeline
    }

    // ---------------- stage V chunks 0,1 early (Kb free after final barrier)
    const int c5base = kstart >> 5;       // -4 for w==0 (P==0 there)
    auto stageV = [&](int h, int buf, int kk) {
        int c5 = c5base + kk; c5 = c5 < 0 ? 0 : c5;
        const unsigned short* src =
            vt3 + (((size_t)(b * 256 + c5)) << 14) + (h << 13);
#pragma unroll
        for (int i = 0; i < 2; ++i)
            gload_lds16(src + (i << 12) + (tid << 3),
                        Kb + (buf << 13) + (i << 12) + (tid << 3));
    };
    stageV(0, 0, 0);
    stageV(0, 1, 1);

    // ---------------- in-register masked softmax (q = l15, keys in-lane) ----
    const float scale = 0.04419417382415922f;  // 512^-0.5
    const int qr = (wid << 4) + l15;           // this lane's q row
    float mx = -3.0e38f;
#pragma unroll
    for (int n = 0; n < 16; ++n)
#pragma unroll
        for (int j = 0; j < 4; ++j) {
            const int c = (n << 4) + (lg << 2) + j;
            const bool keep = (c <= qr + 128) && (w > 0 || c >= 128);
            const float s = keep ? acc[n][j] * scale : -INFINITY;
            acc[n][j] = s;
            mx = fmaxf(mx, s);
        }
    mx = fmaxf(mx, __shfl_xor(mx, 16));
    mx = fmaxf(mx, __shfl_xor(mx, 32));
    float sum = 0.f;
#pragma unroll
    for (int n = 0; n < 16; ++n)
#pragma unroll
        for (int j = 0; j < 4; ++j) {
            const float p = __expf(acc[n][j] - mx);
            acc[n][j] = p;
            sum += p;
        }
    sum += __shfl_xor(sum, 16);
    sum += __shfl_xor(sum, 32);
    const float inv = 1.0f / sum;              // deferred normalization

    // pack P to bf16 pairs: word[n][h] = keys {16n+lg*4+2h, +1}
    unsigned int word[16][2];
#pragma unroll
    for (int n = 0; n < 16; ++n) {
        word[n][0] = pkb(acc[n][0], acc[n][1]);
        word[n][1] = pkb(acc[n][2], acc[n][3]);
    }

    // redistribute to PV B-fragments: pa[kk] = P[q=l15][32kk + lg*8 .. +8]
    bf16x8 pa[8];
#pragma unroll
    for (int kk = 0; kk < 8; ++kk) {
        union { unsigned int w[4]; bf16x8 v; } u;
#pragma unroll
        for (int t = 0; t < 4; ++t) {
            const int src = l15 + (((lg & 1) << 1) + (t >> 1)) * 16;
            const int va = __shfl((int)word[2 * kk][t & 1], src, 64);
            const int vb = __shfl((int)word[2 * kk + 1][t & 1], src, 64);
            u.w[t] = (unsigned int)((lg >> 1) ? vb : va);
        }
        pa[kk] = u.v;
    }

    __syncthreads();   // V chunks 0,1 staged (drains vmcnt), Kb reads done

    // ---------------- phase B: O^T = Vt P^T, dv in 2 halves of 256 ----------
#pragma unroll
    for (int h = 0; h < 2; ++h) {
        if (h) {
            __syncthreads();               // all waves done reading h=0 bufs
            stageV(1, 0, 0);
            stageV(1, 1, 1);
            __syncthreads();
        }
        f32x4 oacc[16];
#pragma unroll
        for (int n = 0; n < 16; ++n) oacc[n] = (f32x4){0.f, 0.f, 0.f, 0.f};

        for (int kk = 0; kk < 8; ++kk) {
            const unsigned short* Vc = Kb + ((kk & 1) << 13);
            const int ko = (lg ^ (l15 & 3)) << 3;   // un-swizzle key octet
#pragma unroll
            for (int n = 0; n < 16; ++n) {
                const bf16x8 vf = *(const bf16x8*)&Vc[(((n << 4) + l15) << 5) + ko];
                // A=Vt (dv rows), B=P -> oacc[n][j] = O[q=l15][dv=16n+lg*4+j]
                oacc[n] = __builtin_amdgcn_mfma_f32_16x16x32_bf16(vf, pa[kk], oacc[n], 0, 0, 0);
            }
            if (kk < 7) {
                __syncthreads();
                if (kk + 2 < 8) stageV(h, kk & 1, kk + 2);
            }
        }

        // epilogue: normalize, float4 stores (dv 16n+lg*4 .. +4)
        float* orow = out + (qrow0 + qr) * DIM + (h << 8) + (lg << 2);
#pragma unroll
        for (int n = 0; n < 16; ++n) {
            float4 f;
            f.x = oacc[n][0] * inv; f.y = oacc[n][1] * inv;
            f.z = oacc[n][2] * inv; f.w = oacc[n][3] * inv;
            *(float4*)&orow[n << 4] = f;
        }
    }
}

// ===========================================================================
extern "C" void kernel_launch(void* const* d_in, const int* in_sizes, int n_in,
                              void* d_out, int out_size, void* d_ws, size_t ws_size,
                              hipStream_t stream) {
    (void)in_sizes; (void)n_in; (void)out_size; (void)ws_size;
    const float* x  = (const float*)d_in[0];
    const float* wq = (const float*)d_in[1];
    const float* bq = (const float*)d_in[2];
    const float* wk = (const float*)d_in[3];
    const float* bk = (const float*)d_in[4];
    const float* wv = (const float*)d_in[5];
    const float* bv = (const float*)d_in[6];
    float* out = (float*)d_out;

    unsigned short* qws  = (unsigned short*)d_ws;
    unsigned short* kws  = qws + WSELEM;
    unsigned short* vtws = kws + WSELEM;

    // xb (64 MiB) + wb (1.5 MiB) live in d_out (128 MiB) — consumed by k_qkv
    // before k_attn overwrites d_out with the final output (stream-ordered).
    unsigned short* xbuf = (unsigned short*)d_out;
    unsigned short* wbuf = xbuf + WSELEM;

    k_cvt<<<2048, 256, 0, stream>>>(x, xbuf, (int)(WSELEM / 8));
    k_cvt<<<128, 256, 0, stream>>>(wq, wbuf, DIM * DIM / 8);
    k_cvt<<<128, 256, 0, stream>>>(wk, wbuf + DIM * DIM, DIM * DIM / 8);
    k_cvt<<<128, 256, 0, stream>>>(wv, wbuf + 2 * DIM * DIM, DIM * DIM / 8);
    k_qkv<<<2048, 256, 0, stream>>>(xbuf, wbuf, bq, bk, bv, qws, kws, vtws);
    k_attn<<<512, 512, 0, stream>>>(qws, kws, vtws, out);
}

// Round 15
// 290.810 us; speedup vs baseline: 1.0155x; 1.0155x over previous
//
#include <hip/hip_runtime.h>

// ---------------------------------------------------------------------------
// Local windowed attention, B=8 N=8192 D=512, WS=128, lookback=1.
//   k_cvt : fp32 -> bf16 convert of x and weights (scratch in d_out).
//   k_qkv : merged Q/K/V projection GEMM (r6 form). Q,K row-major bf16;
//           V in Vt3[b][key/32][dv][key%32] bf16 with key-octet XOR swizzle.
//   k_attn: swapped-operand attention: S^T = mfma(K,Q) puts P per-lane
//           (q = lane&15) -> in-register softmax (no P LDS), P repacked to
//           PV fragments via shfl (incremental: acc dies as pa grows).
//           LDS 64KB (K dbuf / V dbuf union) -> 2 blocks/CU. Phase-B kk loop
//           UNROLLED (r14 bug: runtime pa[kk] index -> scratch spills).
// ---------------------------------------------------------------------------

typedef __bf16 bf16x8 __attribute__((ext_vector_type(8)));
typedef float f32x4 __attribute__((ext_vector_type(4)));
typedef unsigned short u16x8 __attribute__((ext_vector_type(8)));

#define BATCH 8
#define SEQ   8192
#define DIM   512
#define NWIN  64
#define TOKS  (BATCH * SEQ)          // 65536
#define WSELEM ((size_t)TOKS * DIM)  // 33554432 elements per Q/K/V buffer

__device__ __forceinline__ unsigned short f2b(float f) {
    union { float f; unsigned int u; } c; c.f = f;
    unsigned int u = c.u;
    return (unsigned short)((u + 0x7FFFu + ((u >> 16) & 1u)) >> 16);
}
__device__ __forceinline__ unsigned int pkb(float a, float b) {
    return (unsigned int)f2b(a) | ((unsigned int)f2b(b) << 16);
}

// XOR swizzle for [rows][64]-ushort LDS tiles (128B rows).
__device__ __forceinline__ int swz64(int row, int col) {
    return (row * 64 + col) ^ ((row & 7) << 3);
}

__device__ __forceinline__ void gload_lds16(const void* g, void* l) {
    __builtin_amdgcn_global_load_lds(
        (const __attribute__((address_space(1))) void*)g,
        (__attribute__((address_space(3))) void*)l, 16, 0, 0);
}

// ===========================================================================
// Kernel 0: fp32 -> bf16 bulk convert
// ===========================================================================
__global__ __launch_bounds__(256) void k_cvt(const float* __restrict__ s,
                                             unsigned short* __restrict__ d,
                                             int n8) {
    const int stride = gridDim.x * blockDim.x;
    for (int i = blockIdx.x * blockDim.x + threadIdx.x; i < n8; i += stride) {
        const float4 a = ((const float4*)s)[2 * i];
        const float4 b = ((const float4*)s)[2 * i + 1];
        u16x8 v;
        v[0] = f2b(a.x); v[1] = f2b(a.y); v[2] = f2b(a.z); v[3] = f2b(a.w);
        v[4] = f2b(b.x); v[5] = f2b(b.y); v[6] = f2b(b.z); v[7] = f2b(b.w);
        ((u16x8*)d)[i] = v;
    }
}

// ===========================================================================
// Kernel 1: merged QKV projection GEMM (r6). grid = 2048, block = 256.
// ===========================================================================
__global__ __launch_bounds__(256, 2) void k_qkv(
    const unsigned short* __restrict__ xb, const unsigned short* __restrict__ wb,
    const float* __restrict__ bq, const float* __restrict__ bk,
    const float* __restrict__ bv,
    unsigned short* __restrict__ qo, unsigned short* __restrict__ ko,
    unsigned short* __restrict__ vto)
{
    __shared__ __align__(16) unsigned short sm[32768]; // Xs|Wq|Wk|Wv; V-epi T[128][129] aliases
    unsigned short* Xs = sm;

    int bid = (int)blockIdx.x;
    bid = (bid & 7) * 256 + (bid >> 3);   // XCD-contiguous chunks
    const int mt = bid >> 2, nt = bid & 3;
    const int rbase = mt << 7;            // token row base
    const int cbase = nt << 7;            // output feature base

    const unsigned short* __restrict__ xsrc0 = xb + ((size_t)rbase << 9);
    const unsigned short* __restrict__ wsrc0 = wb + ((size_t)cbase << 9);

    const int tid  = threadIdx.x;
    const int lane = tid & 63;
    const int wid  = tid >> 6;
    const int wm = wid >> 1, wn = wid & 1;
    const int l15 = lane & 15, lg = lane >> 4;

    f32x4 acc[3][4][4];
#pragma unroll
    for (int s = 0; s < 3; ++s)
#pragma unroll
        for (int m = 0; m < 4; ++m)
#pragma unroll
            for (int n = 0; n < 4; ++n) acc[s][m][n] = (f32x4){0.f, 0.f, 0.f, 0.f};

    const int srow = tid >> 3;            // 0..31
    const int gs   = ((tid & 7) ^ (srow & 7)) << 3;  // src 16B slot (swizzled)
    const int ldso = tid << 3;

    for (int ks = 0; ks < 8; ++ks) {
        const int kc = ks << 6;
#pragma unroll
        for (int i = 0; i < 4; ++i) {
            const int row = (i << 5) + srow;
            gload_lds16(xsrc0 + ((size_t)row << 9) + kc + gs, Xs + (i << 11) + ldso);
        }
#pragma unroll
        for (int ws = 0; ws < 3; ++ws) {
#pragma unroll
            for (int i = 0; i < 4; ++i) {
                const int row = (i << 5) + srow;
                gload_lds16(wsrc0 + ((size_t)ws << 18) + ((size_t)row << 9) + kc + gs,
                            sm + 8192 + (ws << 13) + (i << 11) + ldso);
            }
        }
        __syncthreads();
#pragma unroll
        for (int kk = 0; kk < 64; kk += 32) {
            const int cu = kk + (lg << 3);
            bf16x8 af[4];
#pragma unroll
            for (int m = 0; m < 4; ++m)
                af[m] = *(const bf16x8*)&Xs[swz64((wm << 6) + (m << 4) + l15, cu)];
#pragma unroll
            for (int ws = 0; ws < 3; ++ws) {
                const unsigned short* Wsb = sm + 8192 + (ws << 13);
                bf16x8 bfr[4];
#pragma unroll
                for (int n = 0; n < 4; ++n)
                    bfr[n] = *(const bf16x8*)&Wsb[swz64((wn << 6) + (n << 4) + l15, cu)];
#pragma unroll
                for (int m = 0; m < 4; ++m)
#pragma unroll
                    for (int n = 0; n < 4; ++n)
                        acc[ws][m][n] = __builtin_amdgcn_mfma_f32_16x16x32_bf16(
                            af[m], bfr[n], acc[ws][m][n], 0, 0, 0);
            }
        }
        __syncthreads();
    }

    // ---- Q/K epilogues: row-major bf16 stores
#pragma unroll
    for (int ws = 0; ws < 2; ++ws) {
        unsigned short* __restrict__ out = ws ? ko : qo;
        const float* __restrict__ bias = ws ? bk : bq;
#pragma unroll
        for (int n = 0; n < 4; ++n) {
            const int col = cbase + (wn << 6) + (n << 4) + l15;
            const float bv_ = bias[col];
#pragma unroll
            for (int m = 0; m < 4; ++m)
#pragma unroll
                for (int j = 0; j < 4; ++j) {
                    const int row = rbase + (wm << 6) + (m << 4) + (lg << 2) + j;
                    out[(size_t)row * DIM + col] = f2b(acc[ws][m][n][j] + bv_);
                }
        }
    }
    // ---- V epilogue: transpose via LDS T[128][129], then wave-contiguous
    //      1KB stores to Vt3[b][key/32][dv][key%32], key-octet XOR'd by dv&3
#pragma unroll
    for (int n = 0; n < 4; ++n) {
        const int dv = (wn << 6) + (n << 4) + l15;
        const float bv_ = bv[cbase + dv];
#pragma unroll
        for (int m = 0; m < 4; ++m)
#pragma unroll
            for (int j = 0; j < 4; ++j) {
                const int tok = (wm << 6) + (m << 4) + (lg << 2) + j;
                sm[tok * 129 + dv] = f2b(acc[2][m][n][j] + bv_);
            }
    }
    __syncthreads();
    {
        const int batch = rbase >> 13;
        const int c5_0  = (rbase & 8191) >> 5;   // key-chunk base (mult of 4)
#pragma unroll
        for (int s = 0; s < 8; ++s) {
            const int c5sel = s & 3, dvh = s >> 2;
            const int dvl  = (dvh << 6) + (wid << 4) + (lane >> 2);  // 0..127
            const int keyo = (lane & 3) << 3;                        // 0,8,16,24
            const int tok0 = (c5sel << 5) + keyo;
            u16x8 v;
#pragma unroll
            for (int j = 0; j < 8; ++j) v[j] = sm[(tok0 + j) * 129 + dvl];
            *(u16x8*)&vto[((size_t)((batch * 256 + c5_0 + c5sel) * 512
                                    + cbase + dvl) << 5)
                          + (keyo ^ ((dvl & 3) << 3))] = v;
        }
    }
}

// ===========================================================================
// Kernel 2: swapped-operand windowed attention. grid = 512 x 512thr (8 waves).
// Wave w owns q-rows [w*16, w*16+16); within a lane, q = lane&15.
// LDS 64KB: phase A K dbuf 2x32KB; phase B V dbuf 2x16KB (aliases). 2 blk/CU.
// ===========================================================================
__global__ __launch_bounds__(512, 4) void k_attn(
    const unsigned short* __restrict__ q,
    const unsigned short* __restrict__ k,
    const unsigned short* __restrict__ vt3,
    float* __restrict__ out)
{
    __shared__ __align__(16) unsigned short Kb[32768];   // 64KB, reused for V

    int bid = (int)blockIdx.x;
    bid = (bid & 7) * 64 + (bid >> 3);    // XCD-chunked: one batch per XCD
    const int b = bid >> 6, w = bid & 63;
    const int tid  = threadIdx.x;
    const int lane = tid & 63, wid = tid >> 6;
    const int l15 = lane & 15, lg = lane >> 4;
    const int kstart = (w - 1) << 7;
    const size_t qrow0 = ((size_t)b << 13) + ((size_t)w << 7);
    const size_t kbase = (size_t)b << 13;

    const int srow = tid >> 3;            // 0..63
    const int s0   = tid & 7;

    // ---------------- phase A: S^T = K Q^T (per-wave 256k x 16q, inner 512) -
    f32x4 acc[16];
#pragma unroll
    for (int n = 0; n < 16; ++n) acc[n] = (f32x4){0.f, 0.f, 0.f, 0.f};

    auto stageK = [&](int buf, int ds) {
#pragma unroll
        for (int i = 0; i < 4; ++i) {
            const int r = (i << 6) + srow;
            int krow = kstart + r; krow = krow < 0 ? 0 : krow;  // masked anyway
            gload_lds16(k + (kbase + krow) * DIM + (ds << 6) + ((s0 ^ (r & 7)) << 3),
                        Kb + (buf << 14) + (i << 12) + (tid << 3));
        }
    };

    stageK(0, 0);
    stageK(1, 1);
    __syncthreads();
#pragma unroll
    for (int ds = 0; ds < 8; ++ds) {
        const unsigned short* Kc = Kb + ((ds & 1) << 14);
#pragma unroll
        for (int kk2 = 0; kk2 < 2; ++kk2) {
            const int cu = (kk2 << 5) + (lg << 3);
            const bf16x8 qf = *(const bf16x8*)
                &q[(qrow0 + (wid << 4) + l15) * DIM + (ds << 6) + cu];
#pragma unroll
            for (int n = 0; n < 16; ++n) {
                const bf16x8 kf = *(const bf16x8*)&Kc[swz64((n << 4) + l15, cu)];
                // SWAPPED: A=K, B=Q -> acc[n][j] = S[q=l15][key=16n+lg*4+j]
                acc[n] = __builtin_amdgcn_mfma_f32_16x16x32_bf16(kf, qf, acc[n], 0, 0, 0);
            }
        }
        __syncthreads();
        if (ds + 2 < 8) stageK(ds & 1, ds + 2);  // 1-deep pipeline
    }

    // ---------------- stage V chunks 0,1 early (Kb free after final barrier)
    const int c5base = kstart >> 5;       // -4 for w==0 (P==0 there)
    auto stageV = [&](int h, int buf, int kk) {
        int c5 = c5base + kk; c5 = c5 < 0 ? 0 : c5;
        const unsigned short* src =
            vt3 + (((size_t)(b * 256 + c5)) << 14) + (h << 13);
#pragma unroll
        for (int i = 0; i < 2; ++i)
            gload_lds16(src + (i << 12) + (tid << 3),
                        Kb + (buf << 13) + (i << 12) + (tid << 3));
    };
    stageV(0, 0, 0);
    stageV(0, 1, 1);

    // ---------------- in-register masked softmax (q = l15, keys in-lane) ----
    const float scale = 0.04419417382415922f;  // 512^-0.5
    const int qr = (wid << 4) + l15;           // this lane's q row
    float mx = -3.0e38f;
#pragma unroll
    for (int n = 0; n < 16; ++n)
#pragma unroll
        for (int j = 0; j < 4; ++j) {
            const int c = (n << 4) + (lg << 2) + j;
            const bool keep = (c <= qr + 128) && (w > 0 || c >= 128);
            const float s = keep ? acc[n][j] * scale : -INFINITY;
            acc[n][j] = s;
            mx = fmaxf(mx, s);
        }
    mx = fmaxf(mx, __shfl_xor(mx, 16));
    mx = fmaxf(mx, __shfl_xor(mx, 32));
    float sum = 0.f;
#pragma unroll
    for (int n = 0; n < 16; ++n)
#pragma unroll
        for (int j = 0; j < 4; ++j) {
            const float p = __expf(acc[n][j] - mx);
            acc[n][j] = p;
            sum += p;
        }
    sum += __shfl_xor(sum, 16);
    sum += __shfl_xor(sum, 32);
    const float inv = 1.0f / sum;              // deferred normalization

    // pack+redistribute to PV B-fragments, incrementally (acc[2kk] dies as
    // pa[kk] is built -> peak live regs ~85, fits the 128 cap, no scratch):
    // pa[kk] = P[q=l15][32kk + lg*8 .. +8]
    bf16x8 pa[8];
#pragma unroll
    for (int kk = 0; kk < 8; ++kk) {
        unsigned int w0[2], w1[2];
        w0[0] = pkb(acc[2 * kk][0], acc[2 * kk][1]);
        w0[1] = pkb(acc[2 * kk][2], acc[2 * kk][3]);
        w1[0] = pkb(acc[2 * kk + 1][0], acc[2 * kk + 1][1]);
        w1[1] = pkb(acc[2 * kk + 1][2], acc[2 * kk + 1][3]);
        union { unsigned int u32[4]; bf16x8 v; } u;
#pragma unroll
        for (int t = 0; t < 4; ++t) {
            const int src = l15 + (((lg & 1) << 1) + (t >> 1)) * 16;
            const int va = __shfl((int)w0[t & 1], src, 64);
            const int vb = __shfl((int)w1[t & 1], src, 64);
            u.u32[t] = (unsigned int)((lg >> 1) ? vb : va);
        }
        pa[kk] = u.v;
    }

    __syncthreads();   // V chunks 0,1 staged (drains vmcnt), Kb reads done

    // ---------------- phase B: O^T = Vt P^T, dv in 2 halves of 256 ----------
#pragma unroll
    for (int h = 0; h < 2; ++h) {
        if (h) {
            __syncthreads();               // all waves done reading h=0 bufs
            stageV(1, 0, 0);
            stageV(1, 1, 1);
            __syncthreads();
        }
        f32x4 oacc[16];
#pragma unroll
        for (int n = 0; n < 16; ++n) oacc[n] = (f32x4){0.f, 0.f, 0.f, 0.f};

#pragma unroll
        for (int kk = 0; kk < 8; ++kk) {   // UNROLLED: pa[kk] must be static
            const unsigned short* Vc = Kb + ((kk & 1) << 13);
            const int ko = (lg ^ (l15 & 3)) << 3;   // un-swizzle key octet
#pragma unroll
            for (int n = 0; n < 16; ++n) {
                const bf16x8 vf = *(const bf16x8*)&Vc[(((n << 4) + l15) << 5) + ko];
                // A=Vt (dv rows), B=P -> oacc[n][j] = O[q=l15][dv=16n+lg*4+j]
                oacc[n] = __builtin_amdgcn_mfma_f32_16x16x32_bf16(vf, pa[kk], oacc[n], 0, 0, 0);
            }
            if (kk < 7) {
                __syncthreads();
                if (kk + 2 < 8) stageV(h, kk & 1, kk + 2);
            }
        }

        // epilogue: normalize, float4 stores (dv 16n+lg*4 .. +4)
        float* orow = out + (qrow0 + qr) * DIM + (h << 8) + (lg << 2);
#pragma unroll
        for (int n = 0; n < 16; ++n) {
            float4 f;
            f.x = oacc[n][0] * inv; f.y = oacc[n][1] * inv;
            f.z = oacc[n][2] * inv; f.w = oacc[n][3] * inv;
            *(float4*)&orow[n << 4] = f;
        }
    }
}

// ===========================================================================
extern "C" void kernel_launch(void* const* d_in, const int* in_sizes, int n_in,
                              void* d_out, int out_size, void* d_ws, size_t ws_size,
                              hipStream_t stream) {
    (void)in_sizes; (void)n_in; (void)out_size; (void)ws_size;
    const float* x  = (const float*)d_in[0];
    const float* wq = (const float*)d_in[1];
    const float* bq = (const float*)d_in[2];
    const float* wk = (const float*)d_in[3];
    const float* bk = (const float*)d_in[4];
    const float* wv = (const float*)d_in[5];
    const float* bv = (const float*)d_in[6];
    float* out = (float*)d_out;

    unsigned short* qws  = (unsigned short*)d_ws;
    unsigned short* kws  = qws + WSELEM;
    unsigned short* vtws = kws + WSELEM;

    // xb (64 MiB) + wb (1.5 MiB) live in d_out (128 MiB) — consumed by k_qkv
    // before k_attn overwrites d_out with the final output (stream-ordered).
    unsigned short* xbuf = (unsigned short*)d_out;
    unsigned short* wbuf = xbuf + WSELEM;

    k_cvt<<<2048, 256, 0, stream>>>(x, xbuf, (int)(WSELEM / 8));
    k_cvt<<<128, 256, 0, stream>>>(wq, wbuf, DIM * DIM / 8);
    k_cvt<<<128, 256, 0, stream>>>(wk, wbuf + DIM * DIM, DIM * DIM / 8);
    k_cvt<<<128, 256, 0, stream>>>(wv, wbuf + 2 * DIM * DIM, DIM * DIM / 8);
    k_qkv<<<2048, 256, 0, stream>>>(xbuf, wbuf, bq, bk, bv, qws, kws, vtws);
    k_attn<<<512, 512, 0, stream>>>(qws, kws, vtws, out);
}

// Round 16
// 250.581 us; speedup vs baseline: 1.1786x; 1.1605x over previous
//
#include <hip/hip_runtime.h>

// ---------------------------------------------------------------------------
// Local windowed attention, B=8 N=8192 D=512, WS=128, lookback=1.
//   k_cvt : fp32 -> bf16 convert of x and weights (scratch in d_out).
//   k_qkv : merged Q/K/V projection GEMM (r6 form). Q,K row-major bf16;
//           V in Vt3[b][key/32][dv][key%32] bf16 with key-octet XOR swizzle.
//   k_attn: swapped-operand attention: S^T = mfma(K,Q) puts P per-lane
//           (q = lane&15) -> in-register softmax (no P LDS), P repacked to
//           PV fragments via shfl. LDS 64KB -> 2 blocks/CU.
//           NOTE __launch_bounds__(512,2): the (512,4) of r14/r15 capped the
//           kernel at 64 VGPRs -> 240MB scratch spills -> 2.2x slowdown.
// ---------------------------------------------------------------------------

typedef __bf16 bf16x8 __attribute__((ext_vector_type(8)));
typedef float f32x4 __attribute__((ext_vector_type(4)));
typedef unsigned short u16x8 __attribute__((ext_vector_type(8)));

#define BATCH 8
#define SEQ   8192
#define DIM   512
#define NWIN  64
#define TOKS  (BATCH * SEQ)          // 65536
#define WSELEM ((size_t)TOKS * DIM)  // 33554432 elements per Q/K/V buffer

__device__ __forceinline__ unsigned short f2b(float f) {
    union { float f; unsigned int u; } c; c.f = f;
    unsigned int u = c.u;
    return (unsigned short)((u + 0x7FFFu + ((u >> 16) & 1u)) >> 16);
}
__device__ __forceinline__ unsigned int pkb(float a, float b) {
    return (unsigned int)f2b(a) | ((unsigned int)f2b(b) << 16);
}

// XOR swizzle for [rows][64]-ushort LDS tiles (128B rows).
__device__ __forceinline__ int swz64(int row, int col) {
    return (row * 64 + col) ^ ((row & 7) << 3);
}

__device__ __forceinline__ void gload_lds16(const void* g, void* l) {
    __builtin_amdgcn_global_load_lds(
        (const __attribute__((address_space(1))) void*)g,
        (__attribute__((address_space(3))) void*)l, 16, 0, 0);
}

// ===========================================================================
// Kernel 0: fp32 -> bf16 bulk convert
// ===========================================================================
__global__ __launch_bounds__(256) void k_cvt(const float* __restrict__ s,
                                             unsigned short* __restrict__ d,
                                             int n8) {
    const int stride = gridDim.x * blockDim.x;
    for (int i = blockIdx.x * blockDim.x + threadIdx.x; i < n8; i += stride) {
        const float4 a = ((const float4*)s)[2 * i];
        const float4 b = ((const float4*)s)[2 * i + 1];
        u16x8 v;
        v[0] = f2b(a.x); v[1] = f2b(a.y); v[2] = f2b(a.z); v[3] = f2b(a.w);
        v[4] = f2b(b.x); v[5] = f2b(b.y); v[6] = f2b(b.z); v[7] = f2b(b.w);
        ((u16x8*)d)[i] = v;
    }
}

// ===========================================================================
// Kernel 1: merged QKV projection GEMM (r6). grid = 2048, block = 256.
// ===========================================================================
__global__ __launch_bounds__(256, 2) void k_qkv(
    const unsigned short* __restrict__ xb, const unsigned short* __restrict__ wb,
    const float* __restrict__ bq, const float* __restrict__ bk,
    const float* __restrict__ bv,
    unsigned short* __restrict__ qo, unsigned short* __restrict__ ko,
    unsigned short* __restrict__ vto)
{
    __shared__ __align__(16) unsigned short sm[32768]; // Xs|Wq|Wk|Wv; V-epi T[128][129] aliases
    unsigned short* Xs = sm;

    int bid = (int)blockIdx.x;
    bid = (bid & 7) * 256 + (bid >> 3);   // XCD-contiguous chunks
    const int mt = bid >> 2, nt = bid & 3;
    const int rbase = mt << 7;            // token row base
    const int cbase = nt << 7;            // output feature base

    const unsigned short* __restrict__ xsrc0 = xb + ((size_t)rbase << 9);
    const unsigned short* __restrict__ wsrc0 = wb + ((size_t)cbase << 9);

    const int tid  = threadIdx.x;
    const int lane = tid & 63;
    const int wid  = tid >> 6;
    const int wm = wid >> 1, wn = wid & 1;
    const int l15 = lane & 15, lg = lane >> 4;

    f32x4 acc[3][4][4];
#pragma unroll
    for (int s = 0; s < 3; ++s)
#pragma unroll
        for (int m = 0; m < 4; ++m)
#pragma unroll
            for (int n = 0; n < 4; ++n) acc[s][m][n] = (f32x4){0.f, 0.f, 0.f, 0.f};

    const int srow = tid >> 3;            // 0..31
    const int gs   = ((tid & 7) ^ (srow & 7)) << 3;  // src 16B slot (swizzled)
    const int ldso = tid << 3;

    for (int ks = 0; ks < 8; ++ks) {
        const int kc = ks << 6;
#pragma unroll
        for (int i = 0; i < 4; ++i) {
            const int row = (i << 5) + srow;
            gload_lds16(xsrc0 + ((size_t)row << 9) + kc + gs, Xs + (i << 11) + ldso);
        }
#pragma unroll
        for (int ws = 0; ws < 3; ++ws) {
#pragma unroll
            for (int i = 0; i < 4; ++i) {
                const int row = (i << 5) + srow;
                gload_lds16(wsrc0 + ((size_t)ws << 18) + ((size_t)row << 9) + kc + gs,
                            sm + 8192 + (ws << 13) + (i << 11) + ldso);
            }
        }
        __syncthreads();
#pragma unroll
        for (int kk = 0; kk < 64; kk += 32) {
            const int cu = kk + (lg << 3);
            bf16x8 af[4];
#pragma unroll
            for (int m = 0; m < 4; ++m)
                af[m] = *(const bf16x8*)&Xs[swz64((wm << 6) + (m << 4) + l15, cu)];
#pragma unroll
            for (int ws = 0; ws < 3; ++ws) {
                const unsigned short* Wsb = sm + 8192 + (ws << 13);
                bf16x8 bfr[4];
#pragma unroll
                for (int n = 0; n < 4; ++n)
                    bfr[n] = *(const bf16x8*)&Wsb[swz64((wn << 6) + (n << 4) + l15, cu)];
#pragma unroll
                for (int m = 0; m < 4; ++m)
#pragma unroll
                    for (int n = 0; n < 4; ++n)
                        acc[ws][m][n] = __builtin_amdgcn_mfma_f32_16x16x32_bf16(
                            af[m], bfr[n], acc[ws][m][n], 0, 0, 0);
            }
        }
        __syncthreads();
    }

    // ---- Q/K epilogues: row-major bf16 stores
#pragma unroll
    for (int ws = 0; ws < 2; ++ws) {
        unsigned short* __restrict__ out = ws ? ko : qo;
        const float* __restrict__ bias = ws ? bk : bq;
#pragma unroll
        for (int n = 0; n < 4; ++n) {
            const int col = cbase + (wn << 6) + (n << 4) + l15;
            const float bv_ = bias[col];
#pragma unroll
            for (int m = 0; m < 4; ++m)
#pragma unroll
                for (int j = 0; j < 4; ++j) {
                    const int row = rbase + (wm << 6) + (m << 4) + (lg << 2) + j;
                    out[(size_t)row * DIM + col] = f2b(acc[ws][m][n][j] + bv_);
                }
        }
    }
    // ---- V epilogue: transpose via LDS T[128][129], then wave-contiguous
    //      1KB stores to Vt3[b][key/32][dv][key%32], key-octet XOR'd by dv&3
#pragma unroll
    for (int n = 0; n < 4; ++n) {
        const int dv = (wn << 6) + (n << 4) + l15;
        const float bv_ = bv[cbase + dv];
#pragma unroll
        for (int m = 0; m < 4; ++m)
#pragma unroll
            for (int j = 0; j < 4; ++j) {
                const int tok = (wm << 6) + (m << 4) + (lg << 2) + j;
                sm[tok * 129 + dv] = f2b(acc[2][m][n][j] + bv_);
            }
    }
    __syncthreads();
    {
        const int batch = rbase >> 13;
        const int c5_0  = (rbase & 8191) >> 5;   // key-chunk base (mult of 4)
#pragma unroll
        for (int s = 0; s < 8; ++s) {
            const int c5sel = s & 3, dvh = s >> 2;
            const int dvl  = (dvh << 6) + (wid << 4) + (lane >> 2);  // 0..127
            const int keyo = (lane & 3) << 3;                        // 0,8,16,24
            const int tok0 = (c5sel << 5) + keyo;
            u16x8 v;
#pragma unroll
            for (int j = 0; j < 8; ++j) v[j] = sm[(tok0 + j) * 129 + dvl];
            *(u16x8*)&vto[((size_t)((batch * 256 + c5_0 + c5sel) * 512
                                    + cbase + dvl) << 5)
                          + (keyo ^ ((dvl & 3) << 3))] = v;
        }
    }
}

// ===========================================================================
// Kernel 2: swapped-operand windowed attention. grid = 512 x 512thr (8 waves).
// Wave w owns q-rows [w*16, w*16+16); within a lane, q = lane&15.
// LDS 64KB: phase A K dbuf 2x32KB; phase B V dbuf 2x16KB (aliases). 2 blk/CU.
// ===========================================================================
__global__ __launch_bounds__(512, 2) void k_attn(
    const unsigned short* __restrict__ q,
    const unsigned short* __restrict__ k,
    const unsigned short* __restrict__ vt3,
    float* __restrict__ out)
{
    __shared__ __align__(16) unsigned short Kb[32768];   // 64KB, reused for V

    int bid = (int)blockIdx.x;
    bid = (bid & 7) * 64 + (bid >> 3);    // XCD-chunked: one batch per XCD
    const int b = bid >> 6, w = bid & 63;
    const int tid  = threadIdx.x;
    const int lane = tid & 63, wid = tid >> 6;
    const int l15 = lane & 15, lg = lane >> 4;
    const int kstart = (w - 1) << 7;
    const size_t qrow0 = ((size_t)b << 13) + ((size_t)w << 7);
    const size_t kbase = (size_t)b << 13;

    const int srow = tid >> 3;            // 0..63
    const int s0   = tid & 7;

    // ---------------- phase A: S^T = K Q^T (per-wave 256k x 16q, inner 512) -
    f32x4 acc[16];
#pragma unroll
    for (int n = 0; n < 16; ++n) acc[n] = (f32x4){0.f, 0.f, 0.f, 0.f};

    auto stageK = [&](int buf, int ds) {
#pragma unroll
        for (int i = 0; i < 4; ++i) {
            const int r = (i << 6) + srow;
            int krow = kstart + r; krow = krow < 0 ? 0 : krow;  // masked anyway
            gload_lds16(k + (kbase + krow) * DIM + (ds << 6) + ((s0 ^ (r & 7)) << 3),
                        Kb + (buf << 14) + (i << 12) + (tid << 3));
        }
    };

    stageK(0, 0);
    stageK(1, 1);
    __syncthreads();
#pragma unroll
    for (int ds = 0; ds < 8; ++ds) {
        const unsigned short* Kc = Kb + ((ds & 1) << 14);
#pragma unroll
        for (int kk2 = 0; kk2 < 2; ++kk2) {
            const int cu = (kk2 << 5) + (lg << 3);
            const bf16x8 qf = *(const bf16x8*)
                &q[(qrow0 + (wid << 4) + l15) * DIM + (ds << 6) + cu];
#pragma unroll
            for (int n = 0; n < 16; ++n) {
                const bf16x8 kf = *(const bf16x8*)&Kc[swz64((n << 4) + l15, cu)];
                // SWAPPED: A=K, B=Q -> acc[n][j] = S[q=l15][key=16n+lg*4+j]
                acc[n] = __builtin_amdgcn_mfma_f32_16x16x32_bf16(kf, qf, acc[n], 0, 0, 0);
            }
        }
        __syncthreads();
        if (ds + 2 < 8) stageK(ds & 1, ds + 2);  // 1-deep pipeline
    }

    // ---------------- stage V chunks 0,1 early (Kb free after final barrier)
    const int c5base = kstart >> 5;       // -4 for w==0 (P==0 there)
    auto stageV = [&](int h, int buf, int kk) {
        int c5 = c5base + kk; c5 = c5 < 0 ? 0 : c5;
        const unsigned short* src =
            vt3 + (((size_t)(b * 256 + c5)) << 14) + (h << 13);
#pragma unroll
        for (int i = 0; i < 2; ++i)
            gload_lds16(src + (i << 12) + (tid << 3),
                        Kb + (buf << 13) + (i << 12) + (tid << 3));
    };
    stageV(0, 0, 0);
    stageV(0, 1, 1);

    // ---------------- in-register masked softmax (q = l15, keys in-lane) ----
    const float scale = 0.04419417382415922f;  // 512^-0.5
    const int qr = (wid << 4) + l15;           // this lane's q row
    float mx = -3.0e38f;
#pragma unroll
    for (int n = 0; n < 16; ++n)
#pragma unroll
        for (int j = 0; j < 4; ++j) {
            const int c = (n << 4) + (lg << 2) + j;
            const bool keep = (c <= qr + 128) && (w > 0 || c >= 128);
            const float s = keep ? acc[n][j] * scale : -INFINITY;
            acc[n][j] = s;
            mx = fmaxf(mx, s);
        }
    mx = fmaxf(mx, __shfl_xor(mx, 16));
    mx = fmaxf(mx, __shfl_xor(mx, 32));
    float sum = 0.f;
#pragma unroll
    for (int n = 0; n < 16; ++n)
#pragma unroll
        for (int j = 0; j < 4; ++j) {
            const float p = __expf(acc[n][j] - mx);
            acc[n][j] = p;
            sum += p;
        }
    sum += __shfl_xor(sum, 16);
    sum += __shfl_xor(sum, 32);
    const float inv = 1.0f / sum;              // deferred normalization

    // pack+redistribute to PV B-fragments, incrementally (acc[2kk] dies as
    // pa[kk] is built): pa[kk] = P[q=l15][32kk + lg*8 .. +8]
    bf16x8 pa[8];
#pragma unroll
    for (int kk = 0; kk < 8; ++kk) {
        unsigned int w0[2], w1[2];
        w0[0] = pkb(acc[2 * kk][0], acc[2 * kk][1]);
        w0[1] = pkb(acc[2 * kk][2], acc[2 * kk][3]);
        w1[0] = pkb(acc[2 * kk + 1][0], acc[2 * kk + 1][1]);
        w1[1] = pkb(acc[2 * kk + 1][2], acc[2 * kk + 1][3]);
        union { unsigned int u32[4]; bf16x8 v; } u;
#pragma unroll
        for (int t = 0; t < 4; ++t) {
            const int src = l15 + (((lg & 1) << 1) + (t >> 1)) * 16;
            const int va = __shfl((int)w0[t & 1], src, 64);
            const int vb = __shfl((int)w1[t & 1], src, 64);
            u.u32[t] = (unsigned int)((lg >> 1) ? vb : va);
        }
        pa[kk] = u.v;
    }

    __syncthreads();   // V chunks 0,1 staged (drains vmcnt), Kb reads done

    // ---------------- phase B: O^T = Vt P^T, dv in 2 halves of 256 ----------
#pragma unroll
    for (int h = 0; h < 2; ++h) {
        if (h) {
            __syncthreads();               // all waves done reading h=0 bufs
            stageV(1, 0, 0);
            stageV(1, 1, 1);
            __syncthreads();
        }
        f32x4 oacc[16];
#pragma unroll
        for (int n = 0; n < 16; ++n) oacc[n] = (f32x4){0.f, 0.f, 0.f, 0.f};

#pragma unroll
        for (int kk = 0; kk < 8; ++kk) {   // unrolled: pa[kk] static
            const unsigned short* Vc = Kb + ((kk & 1) << 13);
            const int ko = (lg ^ (l15 & 3)) << 3;   // un-swizzle key octet
#pragma unroll
            for (int n = 0; n < 16; ++n) {
                const bf16x8 vf = *(const bf16x8*)&Vc[(((n << 4) + l15) << 5) + ko];
                // A=Vt (dv rows), B=P -> oacc[n][j] = O[q=l15][dv=16n+lg*4+j]
                oacc[n] = __builtin_amdgcn_mfma_f32_16x16x32_bf16(vf, pa[kk], oacc[n], 0, 0, 0);
            }
            if (kk < 7) {
                __syncthreads();
                if (kk + 2 < 8) stageV(h, kk & 1, kk + 2);
            }
        }

        // epilogue: normalize, float4 stores (dv 16n+lg*4 .. +4)
        float* orow = out + (qrow0 + qr) * DIM + (h << 8) + (lg << 2);
#pragma unroll
        for (int n = 0; n < 16; ++n) {
            float4 f;
            f.x = oacc[n][0] * inv; f.y = oacc[n][1] * inv;
            f.z = oacc[n][2] * inv; f.w = oacc[n][3] * inv;
            *(float4*)&orow[n << 4] = f;
        }
    }
}

// ===========================================================================
extern "C" void kernel_launch(void* const* d_in, const int* in_sizes, int n_in,
                              void* d_out, int out_size, void* d_ws, size_t ws_size,
                              hipStream_t stream) {
    (void)in_sizes; (void)n_in; (void)out_size; (void)ws_size;
    const float* x  = (const float*)d_in[0];
    const float* wq = (const float*)d_in[1];
    const float* bq = (const float*)d_in[2];
    const float* wk = (const float*)d_in[3];
    const float* bk = (const float*)d_in[4];
    const float* wv = (const float*)d_in[5];
    const float* bv = (const float*)d_in[6];
    float* out = (float*)d_out;

    unsigned short* qws  = (unsigned short*)d_ws;
    unsigned short* kws  = qws + WSELEM;
    unsigned short* vtws = kws + WSELEM;

    // xb (64 MiB) + wb (1.5 MiB) live in d_out (128 MiB) — consumed by k_qkv
    // before k_attn overwrites d_out with the final output (stream-ordered).
    unsigned short* xbuf = (unsigned short*)d_out;
    unsigned short* wbuf = xbuf + WSELEM;

    k_cvt<<<2048, 256, 0, stream>>>(x, xbuf, (int)(WSELEM / 8));
    k_cvt<<<128, 256, 0, stream>>>(wq, wbuf, DIM * DIM / 8);
    k_cvt<<<128, 256, 0, stream>>>(wk, wbuf + DIM * DIM, DIM * DIM / 8);
    k_cvt<<<128, 256, 0, stream>>>(wv, wbuf + 2 * DIM * DIM, DIM * DIM / 8);
    k_qkv<<<2048, 256, 0, stream>>>(xbuf, wbuf, bq, bk, bv, qws, kws, vtws);
    k_attn<<<512, 512, 0, stream>>>(qws, kws, vtws, out);
}